// Round 9
// baseline (831.408 us; speedup 1.0000x reference)
//
#include <hip/hip_runtime.h>

#define D 64
#define NPB_SHIFT 9                    // 512 dst nodes per bucket
#define NPB (1 << NPB_SHIFT)
#define NB 196                         // ceil(100000/512)
#define CHUNK 8192                     // edges per multisplit block (32 KB LDS stage)

// ---------- K0: f32 -> bf16(RNE) packed feature tables ----------
__device__ __forceinline__ unsigned bf16rne(float x) {
    unsigned u = __float_as_uint(x);
    return (u + 0x7fffu + ((u >> 16) & 1u)) >> 16;
}
__global__ __launch_bounds__(256) void to_bf16(
    const float* __restrict__ fu, const float* __restrict__ fi,
    unsigned* __restrict__ bu, unsigned* __restrict__ bi, int n4)
{
    const float4* src = blockIdx.y == 0 ? (const float4*)fu : (const float4*)fi;
    uint2* dst = blockIdx.y == 0 ? (uint2*)bu : (uint2*)bi;
    for (int i = blockIdx.x * 256 + threadIdx.x; i < n4; i += gridDim.x * 256) {
        const float4 v = src[i];
        uint2 r;
        r.x = bf16rne(v.x) | (bf16rne(v.y) << 16);
        r.y = bf16rne(v.z) | (bf16rne(v.w) << 16);
        dst[i] = r;
    }
}

// ---------- K1: per-(etype,bucket) histogram, LDS-aggregated ----------
__global__ __launch_bounds__(256) void bkt_hist(
    const int* __restrict__ d0, const int* __restrict__ d1, const int* __restrict__ d2,
    int* __restrict__ hist, int nE)
{
    const int et = blockIdx.y;
    const int* dst = et == 0 ? d0 : (et == 1 ? d1 : d2);
    __shared__ int h[NB];
    for (int i = threadIdx.x; i < NB; i += 256) h[i] = 0;
    __syncthreads();
    for (int e = blockIdx.x * 256 + threadIdx.x; e < nE; e += gridDim.x * 256)
        atomicAdd(&h[dst[e] >> NPB_SHIFT], 1);
    __syncthreads();
    int* gh = hist + et * NB;
    for (int i = threadIdx.x; i < NB; i += 256)
        if (h[i]) atomicAdd(&gh[i], h[i]);
}

// ---------- K2: exclusive scan of hist[et][0..NB) -> off; init gcur ----------
__global__ __launch_bounds__(256) void bkt_scan(
    const int* __restrict__ hist, int* __restrict__ off, int* __restrict__ gcur)
{
    const int et = blockIdx.x;
    const int tid = threadIdx.x;
    const int v = tid < NB ? hist[et * NB + tid] : 0;
    int inc = v;
#pragma unroll
    for (int of = 1; of < 64; of <<= 1) {
        int t = __shfl_up(inc, of);
        if ((tid & 63) >= of) inc += t;
    }
    __shared__ int ws[4];
    if ((tid & 63) == 63) ws[tid >> 6] = inc;
    __syncthreads();
    int woff = 0;
    for (int i = 0; i < (tid >> 6); ++i) woff += ws[i];
    const int excl = woff + inc - v;
    if (tid < NB) { off[et * NB + tid] = excl; gcur[et * NB + tid] = excl; }
}

// ---------- K3: LDS multisplit scatter into bucket regions ----------
__global__ __launch_bounds__(256) void bkt_multisplit(
    const int* __restrict__ s0, const int* __restrict__ d0,
    const int* __restrict__ s1, const int* __restrict__ d1,
    const int* __restrict__ s2, const int* __restrict__ d2,
    int* __restrict__ gcur, int* __restrict__ bkt, int nE, int E)
{
    const int et = blockIdx.y;
    const int* src = et == 0 ? s0 : (et == 1 ? s1 : s2);
    const int* dst = et == 0 ? d0 : (et == 1 ? d1 : d2);
    int* gc = gcur + et * NB;
    int* bk = bkt + (size_t)et * E;

    __shared__ int h[NB];
    __shared__ int st[NB];
    __shared__ int cu[NB];
    __shared__ int gb[NB];
    __shared__ int ws[4];
    __shared__ int stage[CHUNK];

    const int tid = threadIdx.x;
    const int e0 = blockIdx.x * CHUNK;
    const int e1 = min(e0 + CHUNK, nE);

    for (int i = tid; i < NB; i += 256) h[i] = 0;
    __syncthreads();
    for (int e = e0 + tid; e < e1; e += 256)
        atomicAdd(&h[dst[e] >> NPB_SHIFT], 1);
    __syncthreads();

    const int v = tid < NB ? h[tid] : 0;
    int inc = v;
#pragma unroll
    for (int of = 1; of < 64; of <<= 1) {
        int t = __shfl_up(inc, of);
        if ((tid & 63) >= of) inc += t;
    }
    if ((tid & 63) == 63) ws[tid >> 6] = inc;
    __syncthreads();
    int woff = 0;
    for (int i = 0; i < (tid >> 6); ++i) woff += ws[i];
    const int excl = woff + inc - v;
    if (tid < NB) {
        st[tid] = excl;
        cu[tid] = excl;
        if (v > 0) gb[tid] = atomicAdd(&gc[tid], v);
    }
    __syncthreads();

    for (int e = e0 + tid; e < e1; e += 256) {
        const int dd = dst[e];
        const int b = dd >> NPB_SHIFT;
        const int pos = atomicAdd(&cu[b], 1);
        stage[pos] = src[e] | ((dd & (NPB - 1)) << 17);
    }
    __syncthreads();

    const int wv = tid >> 6, ln = tid & 63;
    for (int b = wv; b < NB; b += 4) {
        const int cb = h[b];
        if (cb == 0) continue;
        const int base = st[b], g = gb[b];
        for (int i = ln; i < cb; i += 64)
            bk[g + i] = stage[base + i];
    }
}

// ---------- K4: per-bucket CSR finalize ----------
__global__ __launch_bounds__(256) void bkt_csr(
    const int* __restrict__ off, const int* __restrict__ bkt_all,
    int* __restrict__ rp_all, int* __restrict__ cnt_all, int* __restrict__ lst_all,
    int N, int E)
{
    const int et = blockIdx.y;
    const int b = blockIdx.x;
    const int* o = off + et * NB;
    const int* bk = bkt_all + (size_t)et * E;
    int* lst = lst_all + (size_t)et * E;
    int* rp  = rp_all  + (size_t)et * N;
    int* cnt = cnt_all + (size_t)et * N;
    const int A  = o[b];
    const int Bb = (b + 1 < NB) ? o[b + 1] : E;

    __shared__ int h[NPB];
    __shared__ int cu[NPB];
    __shared__ int ws2[4];
    for (int i = threadIdx.x; i < NPB; i += 256) h[i] = 0;
    __syncthreads();
    for (int i = A + threadIdx.x; i < Bb; i += 256)
        atomicAdd(&h[((unsigned)bk[i]) >> 17], 1);
    __syncthreads();

    const int tid = threadIdx.x;
    const int v0 = h[2 * tid], v1 = h[2 * tid + 1];
    const int tsum = v0 + v1;
    int inc = tsum;
#pragma unroll
    for (int of = 1; of < 64; of <<= 1) {
        int t = __shfl_up(inc, of);
        if ((tid & 63) >= of) inc += t;
    }
    if ((tid & 63) == 63) ws2[tid >> 6] = inc;
    __syncthreads();
    int woff = 0;
    for (int i = 0; i < (tid >> 6); ++i) woff += ws2[i];
    const int excl = woff + inc - tsum;
    cu[2 * tid] = excl;
    cu[2 * tid + 1] = excl + v0;
    const int n0 = b << NPB_SHIFT;
    if (n0 + 2 * tid < N)     { cnt[n0 + 2 * tid]     = v0; rp[n0 + 2 * tid]     = A + excl; }
    if (n0 + 2 * tid + 1 < N) { cnt[n0 + 2 * tid + 1] = v1; rp[n0 + 2 * tid + 1] = A + excl + v0; }
    __syncthreads();

    for (int i = A + threadIdx.x; i < Bb; i += 256) {
        const int w = bk[i];
        const int dl = ((unsigned)w) >> 17;
        const int pos = atomicAdd(&cu[dl], 1);
        lst[A + pos] = w & 0x1FFFF;
    }
}

// ---------- K5: gather + mean + projection, 4 nodes per wave ----------
// All 4 nodes' idx loads, then all 4 nodes' feature loads issue back-to-back:
// 32 feature loads in flight per wave (vs 8), amortizing the per-node latency chain.
template <bool RMW>
__global__ __launch_bounds__(256) void gather_proj4(
    const unsigned* __restrict__ feat,   // packed rows: 32 uints (= 64 bf16) per node
    const int* __restrict__ rp, const int* __restrict__ cnt, const int* __restrict__ lst,
    const float* __restrict__ W, const float* __restrict__ bias,
    float* __restrict__ out, int N)
{
    __shared__ float2 WTp[32][64];   // WTp[k][o] = (W[o][2k], W[o][2k+1])
    __shared__ float bs[64];
    for (int i = threadIdx.x; i < 2048; i += 256) {
        const int kk = i >> 6, oo = i & 63;
        WTp[kk][oo] = make_float2(W[oo * 64 + 2 * kk], W[oo * 64 + 2 * kk + 1]);
    }
    if (threadIdx.x < 64) bs[threadIdx.x] = bias[threadIdx.x];
    __syncthreads();

    const int tid = threadIdx.x;
    const int lane = tid & 63;
    const int k = lane & 31;      // dim-pair index (dims 2k, 2k+1)
    const int p = lane >> 5;      // edge parity
    const int nbase = blockIdx.x * 16 + (tid >> 6) * 4;

    int deg[4], start[4];
#pragma unroll
    for (int q = 0; q < 4; ++q) {
        const int n = nbase + q;
        deg[q] = (n < N) ? cnt[n] : 0;
        start[q] = (n < N && deg[q] > 0) ? rp[n] : 0;
    }
    const int maxdeg = max(max(deg[0], deg[1]), max(deg[2], deg[3]));

    float sx[4] = {0, 0, 0, 0}, sy[4] = {0, 0, 0, 0};
    if (maxdeg > 0) {
        int id[4][8];
#pragma unroll
        for (int q = 0; q < 4; ++q) {
            const int dm1 = deg[q] > 0 ? deg[q] - 1 : 0;
#pragma unroll
            for (int j = 0; j < 8; ++j) {
                const int ee = 2 * j + p;
                id[q][j] = lst[start[q] + (ee < dm1 ? ee : dm1)];
            }
        }
        for (int e = 0; e < maxdeg; e += 16) {
            unsigned w[4][8];
#pragma unroll
            for (int q = 0; q < 4; ++q)
#pragma unroll
                for (int j = 0; j < 8; ++j)
                    w[q][j] = feat[id[q][j] * 32 + k];   // 32 loads in flight
            const bool more = (e + 16) < maxdeg;         // wave-uniform
            int id2[4][8];
            if (more) {                                  // prefetch next batch idx
#pragma unroll
                for (int q = 0; q < 4; ++q) {
                    const int dm1 = deg[q] > 0 ? deg[q] - 1 : 0;
#pragma unroll
                    for (int j = 0; j < 8; ++j) {
                        const int ee = e + 16 + 2 * j + p;
                        id2[q][j] = lst[start[q] + (ee < dm1 ? ee : dm1)];
                    }
                }
            }
#pragma unroll
            for (int q = 0; q < 4; ++q)
#pragma unroll
                for (int j = 0; j < 8; ++j) {
                    const int ee = e + 2 * j + p;
                    const float m = ee < deg[q] ? 1.0f : 0.0f;
                    sx[q] = fmaf(m, __uint_as_float(w[q][j] << 16), sx[q]);
                    sy[q] = fmaf(m, __uint_as_float(w[q][j] & 0xffff0000u), sy[q]);
                }
            if (more) {
#pragma unroll
                for (int q = 0; q < 4; ++q)
#pragma unroll
                    for (int j = 0; j < 8; ++j) id[q][j] = id2[q][j];
            }
        }
    }

    float mx[4], my[4], a0[4], a1[4];
#pragma unroll
    for (int q = 0; q < 4; ++q) {
        sx[q] += __shfl_xor(sx[q], 32);
        sy[q] += __shfl_xor(sy[q], 32);
        const float inv = deg[q] > 0 ? 1.0f / (float)deg[q] : 0.0f;
        mx[q] = sx[q] * inv;
        my[q] = sy[q] * inv;
        a0[q] = deg[q] > 0 ? bs[lane] : 0.0f;
        a1[q] = 0.0f;
    }
#pragma unroll
    for (int k2 = 0; k2 < 32; ++k2) {
        const float2 wv = WTp[k2][lane];   // one LDS read serves 4 nodes
#pragma unroll
        for (int q = 0; q < 4; ++q) {
            a0[q] = fmaf(__shfl(mx[q], k2), wv.x, a0[q]);
            a1[q] = fmaf(__shfl(my[q], k2), wv.y, a1[q]);
        }
    }
#pragma unroll
    for (int q = 0; q < 4; ++q) {
        const int n = nbase + q;
        if (n < N) {
            float r = a0[q] + a1[q];
            if (RMW) r += out[(size_t)n * D + lane];
            out[(size_t)n * D + lane] = r;
        }
    }
}

extern "C" void kernel_launch(void* const* d_in, const int* in_sizes, int n_in,
                              void* d_out, int out_size, void* d_ws, size_t ws_size,
                              hipStream_t stream)
{
    const float* feat_user = (const float*)d_in[0];
    const float* feat_item = (const float*)d_in[1];
    const float* W_f  = (const float*)d_in[2];
    const float* b_f  = (const float*)d_in[3];
    const float* W_r  = (const float*)d_in[4];
    const float* b_r  = (const float*)d_in[5];
    const float* W_rb = (const float*)d_in[6];
    const float* b_rb = (const float*)d_in[7];
    const int* src_f  = (const int*)d_in[8];
    const int* dst_f  = (const int*)d_in[9];
    const int* src_r  = (const int*)d_in[10];
    const int* dst_r  = (const int*)d_in[11];
    const int* src_rb = (const int*)d_in[12];
    const int* dst_rb = (const int*)d_in[13];
    float* out = (float*)d_out;

    const int NU = in_sizes[0] / D;   // 100000
    const int NI = in_sizes[1] / D;   // 100000 (== NU)
    const int E  = in_sizes[8];       // 1.6M per etype
    const int N  = NU;

    // Workspace (ints then packed bf16 tables); ~66 MB
    int* hist = (int*)d_ws;           // [3][NB]
    int* off  = hist + 3 * NB;
    int* gcur = off  + 3 * NB;
    int* rp   = gcur + 3 * NB;        // [3][N]
    int* cnt  = rp   + 3 * (size_t)N;
    int* bkt  = cnt  + 3 * (size_t)N; // [3][E]
    int* lst  = bkt  + 3 * (size_t)E; // [3][E]
    unsigned* fbu = (unsigned*)(lst + 3 * (size_t)E);  // [N*32] packed bf16 user feats
    unsigned* fbi = fbu + (size_t)N * 32;              // [N*32] packed bf16 item feats

    hipMemsetAsync(hist, 0, (size_t)3 * NB * sizeof(int), stream);

    const dim3 blk(256);
    const int n4 = N * D / 4;
    to_bf16<<<dim3(2048, 2), blk, 0, stream>>>(feat_user, feat_item, fbu, fbi, n4);

    // etype order: 0=follows(dst user), 1=ratedby(dst user), 2=rates(dst item)
    bkt_hist<<<dim3(256, 3), blk, 0, stream>>>(dst_f, dst_rb, dst_r, hist, E);
    bkt_scan<<<3, blk, 0, stream>>>(hist, off, gcur);
    const int nms = (E + CHUNK - 1) / CHUNK;
    bkt_multisplit<<<dim3(nms, 3), blk, 0, stream>>>(
        src_f, dst_f, src_rb, dst_rb, src_r, dst_r, gcur, bkt, E, E);
    bkt_csr<<<dim3(NB, 3), blk, 0, stream>>>(off, bkt, rp, cnt, lst, N, E);

    int* rp_f  = rp;            int* cnt_f  = cnt;            int* lst_f  = lst;
    int* rp_rb = rp + N;        int* cnt_rb = cnt + N;        int* lst_rb = lst + E;
    int* rp_r  = rp + 2 * N;    int* cnt_r  = cnt + 2 * N;    int* lst_r  = lst + 2 * (size_t)E;

    const int gblk = (N + 15) / 16;   // 4 waves/block, 4 nodes/wave
    // users: follows (store), then ratedby (RMW) -> cross-etype sum
    gather_proj4<false><<<gblk, blk, 0, stream>>>(
        fbu, rp_f, cnt_f, lst_f, W_f, b_f, out, NU);
    gather_proj4<true><<<gblk, blk, 0, stream>>>(
        fbi, rp_rb, cnt_rb, lst_rb, W_rb, b_rb, out, NU);
    // items: rates (store)
    gather_proj4<false><<<gblk, blk, 0, stream>>>(
        fbu, rp_r, cnt_r, lst_r, W_r, b_r, out + (size_t)NU * D, NI);
}